// Round 19
// baseline (65.050 us; speedup 1.0000x reference)
//
#include <hip/hip_runtime.h>

typedef __attribute__((ext_vector_type(8))) short bf16x8;
typedef __attribute__((ext_vector_type(8))) unsigned short ushort8;
typedef __attribute__((ext_vector_type(4))) float f32x4;

static __device__ __forceinline__ unsigned short f2bf(float f) {
  union { float f; unsigned u; } v; v.f = f;
  unsigned r = v.u + 0x7FFFu + ((v.u >> 16) & 1u);
  return (unsigned short)(r >> 16);
}
static __device__ __forceinline__ int iclamp(int x, int lo, int hi) {
  return x < lo ? lo : (x > hi ? hi : x);
}
// async global->LDS, 16B per lane; LDS dest = wave-uniform base + lane*16
static __device__ __forceinline__ void gl_lds16(const unsigned short* g,
                                                unsigned short* l) {
  __builtin_amdgcn_global_load_lds(
      (const __attribute__((address_space(1))) void*)g,
      (__attribute__((address_space(3))) void*)l, 16, 0, 0);
}

// ---------------- fused fp32 -> bf16 converts (one launch) ----------------
__global__ void cvt_all(const float* __restrict__ x,
                        const float* __restrict__ w_in,
                        const float* __restrict__ w_out,
                        unsigned short* __restrict__ xb,
                        unsigned short* __restrict__ wbin,
                        unsigned short* __restrict__ wbo) {
  const int NX4 = 1048576, NWI4 = 196608, NWO4 = 65536;  // float4 counts
  const int total = NX4 + NWI4 + NWO4;
  for (int i = blockIdx.x * blockDim.x + threadIdx.x; i < total;
       i += gridDim.x * blockDim.x) {
    const float* src;
    unsigned short* dst;
    int o;
    if (i < NX4) {
      src = x; dst = xb; o = i;
    } else if (i < NX4 + NWI4) {
      src = w_in; dst = wbin; o = i - NX4;
    } else {
      src = w_out; dst = wbo; o = i - NX4 - NWI4;
    }
    float4 v = reinterpret_cast<const float4*>(src)[o];
    ushort4 u;
    u.x = f2bf(v.x); u.y = f2bf(v.y); u.z = f2bf(v.z); u.w = f2bf(v.w);
    reinterpret_cast<ushort4*>(dst)[o] = u;
  }
}

// ------- GEMM1 (r14-best): C[M][N](bf16) = A[M][K] * B[N][K]^T + bias -------
// 128x128 tile, BK=32, 2-phase dbuf, gl_lds w16 pre-swizzled source,
// post-MFMA drain, vectorized epilogue via C-restage. LDS 32 KB -> 4 blk/CU.
__global__ __launch_bounds__(256) void gemm_bt(
    const unsigned short* __restrict__ A, const unsigned short* __restrict__ B,
    const float* __restrict__ bias, unsigned short* __restrict__ C,
    int M, int N, int K) {
  __shared__ unsigned short As[2][128][32];
  __shared__ unsigned short Bs[2][128][32];
  const int tid = threadIdx.x;
  const int lane = tid & 63;
  const int wid = tid >> 6;

  const int nwg = gridDim.x * gridDim.y;
  const int orig = blockIdx.y * gridDim.x + blockIdx.x;
  const int q = nwg >> 3, r = nwg & 7;
  const int xcd = orig & 7, lid = orig >> 3;
  const int swz = (xcd < r ? xcd * (q + 1) : r * (q + 1) + (xcd - r) * q) + lid;
  const int bm = (swz / gridDim.x) * 128;
  const int bn = (swz % gridDim.x) * 128;

  const int wr = (wid >> 1) * 64;
  const int wc = (wid & 1) * 64;
  const int row16 = lane & 15;
  const int kgrp = lane >> 4;
  const int rsw = row16 & 3;

  const int srA = wid * 32 + (lane >> 2);
  const int srB = wid * 32 + (lane >> 2);
  const int lch = (lane & 3) ^ ((lane >> 2) & 3);
  const unsigned short* gA = A + (size_t)(bm + srA) * K + lch * 8;
  const unsigned short* gB = B + (size_t)(bn + srB) * K + lch * 8;
  const size_t K16 = (size_t)16 * K;

#define STAGE(buf, k0)                                                  \
  {                                                                     \
    _Pragma("unroll") for (int j = 0; j < 2; ++j)                       \
        gl_lds16(gA + j * K16 + (k0), &As[buf][wid * 32 + j * 16][0]);  \
    _Pragma("unroll") for (int j = 0; j < 2; ++j)                       \
        gl_lds16(gB + j * K16 + (k0), &Bs[buf][wid * 32 + j * 16][0]);  \
  }

  f32x4 acc[4][4] = {};

  STAGE(0, 0);
  asm volatile("s_waitcnt vmcnt(0)" ::: "memory");
  __builtin_amdgcn_s_barrier();

  const int NT = K >> 5;
  for (int t = 0; t < NT; ++t) {
    const int cur = t & 1;
    if (t + 1 < NT) STAGE(cur ^ 1, (t + 1) * 32);
    bf16x8 af[4], bfr[4];
#pragma unroll
    for (int mi = 0; mi < 4; ++mi)
      af[mi] = *reinterpret_cast<const bf16x8*>(
          &As[cur][wr + mi * 16 + row16][(kgrp ^ rsw) * 8]);
#pragma unroll
    for (int ni = 0; ni < 4; ++ni)
      bfr[ni] = *reinterpret_cast<const bf16x8*>(
          &Bs[cur][wc + ni * 16 + row16][(kgrp ^ rsw) * 8]);
#pragma unroll
    for (int mi = 0; mi < 4; ++mi)
#pragma unroll
      for (int ni = 0; ni < 4; ++ni)
        acc[mi][ni] = __builtin_amdgcn_mfma_f32_16x16x32_bf16(
            af[mi], bfr[ni], acc[mi][ni], 0, 0, 0);
    asm volatile("s_waitcnt vmcnt(0)" ::: "memory");
    __builtin_amdgcn_s_barrier();
  }
#undef STAGE

  // vectorized epilogue via C-restage in As (free now)
  unsigned short* Cs = &As[0][0][0];
#pragma unroll
  for (int ni = 0; ni < 4; ++ni) {
    const float bv = bias[bn + wc + ni * 16 + row16];
#pragma unroll
    for (int mi = 0; mi < 4; ++mi)
#pragma unroll
      for (int r2 = 0; r2 < 4; ++r2)
        Cs[(wr + mi * 16 + kgrp * 4 + r2) * 128 + wc + ni * 16 + row16] =
            f2bf(acc[mi][ni][r2] + bv);
  }
  __syncthreads();
#pragma unroll
  for (int j = 0; j < 8; ++j) {
    const int row = j * 16 + (tid >> 4);
    const int col = (tid & 15) * 8;
    ushort8 v = *reinterpret_cast<const ushort8*>(&Cs[row * 128 + col]);
    *reinterpret_cast<ushort8*>(&C[(size_t)(bm + row) * N + bn + col]) = v;
  }
}

// ---------- FUSED local attention + out-projection ----------
// Block: 32 queries (q0..q0+31) x ALL 8 heads x full out[32][512] row block.
// 4 waves; pair p=wid>>1 handles head 2t+p (t=0..3); pw=wid&1 owns 16 queries.
// Per t: A{V-stage both heads, QK^T, softmax, Ps} bar B{PV -> Cs tile} bar
//        C{out-proj: acc[2][8] += Cs x w_out^T} bar.
// Kills the ctx 16MB write + 16MB read of the separate gemm2.
__global__ __launch_bounds__(256) void attn_oproj(
    const unsigned short* __restrict__ qkv, const unsigned short* __restrict__ wo,
    const float* __restrict__ b_out, float* __restrict__ out, int S) {
  __shared__ unsigned Vt[2][64][58];         // 29696 B; 96 keys + pad, packed pairs
  __shared__ unsigned short Ps[4][16][104];  // 13312 B (v3 width: 2-way banks)
  __shared__ unsigned short Cs[32][136];     // 8704 B ctx tile (2 heads wide)

  const int tid = threadIdx.x;
  const int lane = tid & 63;
  const int wid = tid >> 6;
  const int p = wid >> 1;   // head-pair slot
  const int pw = wid & 1;   // 16-query tile within the 32

  // XCD-chunked bijective swizzle: nwg = 256 (multiple of 8)
  const int orig = blockIdx.y * gridDim.x + blockIdx.x;
  const int swz = (orig & 7) * 32 + (orig >> 3);
  const int q0 = (swz & 127) * 32;  // q-block within sequence
  const int b = swz >> 7;
  const size_t bS = (size_t)b * S;

  const int row16 = lane & 15;
  const int kgrp = lane >> 4;
  const int ccol = row16;
  const int crow4 = kgrp * 4;

  f32x4 oacc[2][8] = {};  // out[32][wid*128 .. +127]

  for (int t = 0; t < 4; ++t) {
    const int h = 2 * t + p;

    // ---- phase A: stage V (both heads of this t), QK^T, softmax, Ps ----
    // V window: keys q0-32 .. q0+63 (96 keys = 48 pairs) per head
    for (int s = tid; s < 384; s += 256) {
      const int hh = s / 192;
      const int rem = s - hh * 192;
      const int k2 = rem >> 2;          // pair 0..47
      const int dq = (rem & 3) * 16;
      const int hv = 2 * t + hh;
      const int ra = iclamp(q0 - 32 + 2 * k2, 0, S - 1);
      const int rb = iclamp(q0 - 32 + 2 * k2 + 1, 0, S - 1);
      const unsigned short* pa = qkv + (bS + ra) * 1536 + 1024 + hv * 64 + dq;
      const unsigned short* pb = qkv + (bS + rb) * 1536 + 1024 + hv * 64 + dq;
      ushort8 a0 = reinterpret_cast<const ushort8*>(pa)[0];
      ushort8 a1 = reinterpret_cast<const ushort8*>(pa)[1];
      ushort8 b0 = reinterpret_cast<const ushort8*>(pb)[0];
      ushort8 b1 = reinterpret_cast<const ushort8*>(pb)[1];
#pragma unroll
      for (int d = 0; d < 8; ++d) {
        Vt[hh][dq + d][k2] = (unsigned)a0[d] | ((unsigned)b0[d] << 16);
        Vt[hh][dq + 8 + d][k2] = (unsigned)a1[d] | ((unsigned)b1[d] << 16);
      }
    }
    if (tid < 128) {  // zero pad dwords 48..55 (keys 96..111: P=0, V finite)
      const int rr = tid & 63;
      const int hh = tid >> 6;
#pragma unroll
      for (int j = 48; j < 56; ++j) Vt[hh][rr][j] = 0u;
    }

    // Q fragments
    const unsigned short* qp =
        qkv + (bS + q0 + pw * 16 + row16) * 1536 + h * 64;
    bf16x8 qf0 = *reinterpret_cast<const bf16x8*>(qp + kgrp * 8);
    bf16x8 qf1 = *reinterpret_cast<const bf16x8*>(qp + 32 + kgrp * 8);

    // QK^T: 5 key tiles (window base q0-32 + pw*16)
    f32x4 sc[5];
#pragma unroll
    for (int tt = 0; tt < 5; ++tt) {
      const int key = iclamp(q0 - 32 + (pw + tt) * 16 + row16, 0, S - 1);
      const unsigned short* kp = qkv + (bS + key) * 1536 + 512 + h * 64;
      bf16x8 kf0 = *reinterpret_cast<const bf16x8*>(kp + kgrp * 8);
      bf16x8 kf1 = *reinterpret_cast<const bf16x8*>(kp + 32 + kgrp * 8);
      f32x4 s = {0.f, 0.f, 0.f, 0.f};
      s = __builtin_amdgcn_mfma_f32_16x16x32_bf16(qf0, kf0, s, 0, 0, 0);
      s = __builtin_amdgcn_mfma_f32_16x16x32_bf16(qf1, kf1, s, 0, 0, 0);
      sc[tt] = s;
    }

    // mask + softmax (diff formula is pw-independent)
    float rm[4] = {-INFINITY, -INFINITY, -INFINITY, -INFINITY};
#pragma unroll
    for (int tt = 0; tt < 5; ++tt)
#pragma unroll
      for (int r = 0; r < 4; ++r) {
        const int key_abs = q0 - 32 + (pw + tt) * 16 + ccol;
        const int diff = -32 + tt * 16 + ccol - crow4 - r;
        float s = sc[tt][r] * 0.125f;
        const bool valid =
            (diff >= -32) && (diff <= 32) && (key_abs >= 0) && (key_abs < S);
        s = valid ? s : -INFINITY;
        sc[tt][r] = s;
        rm[r] = fmaxf(rm[r], s);
      }
#pragma unroll
    for (int off = 1; off < 16; off <<= 1)
#pragma unroll
      for (int r = 0; r < 4; ++r) rm[r] = fmaxf(rm[r], __shfl_xor(rm[r], off, 64));
    float rs[4] = {0.f, 0.f, 0.f, 0.f};
#pragma unroll
    for (int tt = 0; tt < 5; ++tt)
#pragma unroll
      for (int r = 0; r < 4; ++r) {
        const float pv = __expf(sc[tt][r] - rm[r]);
        sc[tt][r] = pv;
        rs[r] += pv;
      }
#pragma unroll
    for (int off = 1; off < 16; off <<= 1)
#pragma unroll
      for (int r = 0; r < 4; ++r) rs[r] += __shfl_xor(rs[r], off, 64);

    // P -> LDS, zero-pad cols 80..95
#pragma unroll
    for (int tt = 0; tt < 5; ++tt)
#pragma unroll
      for (int r = 0; r < 4; ++r)
        Ps[wid][crow4 + r][tt * 16 + ccol] = f2bf(sc[tt][r]);
#pragma unroll
    for (int j = 0; j < 4; ++j) Ps[wid][row16][80 + kgrp * 4 + j] = 0;

    __syncthreads();  // Vt + Ps visible

    // ---- phase B: PV -> ctx sub-tile, normalize, write Cs ----
    f32x4 cacc[4] = {};
#pragma unroll
    for (int kc = 0; kc < 3; ++kc) {
      bf16x8 pf =
          *reinterpret_cast<const bf16x8*>(&Ps[wid][row16][kc * 32 + kgrp * 8]);
#pragma unroll
      for (int ni = 0; ni < 4; ++ni) {
        // dword idx = pw*8 + kc*16 + kgrp*4 -> keys pw*16 + kc*32 + kgrp*8
        bf16x8 vf = *reinterpret_cast<const bf16x8*>(
            &Vt[p][ni * 16 + row16][pw * 8 + kc * 16 + kgrp * 4]);
        cacc[ni] = __builtin_amdgcn_mfma_f32_16x16x32_bf16(pf, vf, cacc[ni], 0, 0, 0);
      }
    }
    float inv[4];
#pragma unroll
    for (int r = 0; r < 4; ++r) inv[r] = 1.0f / rs[r];
#pragma unroll
    for (int ni = 0; ni < 4; ++ni)
#pragma unroll
      for (int r = 0; r < 4; ++r)
        Cs[pw * 16 + crow4 + r][p * 64 + ni * 16 + ccol] =
            f2bf(cacc[ni][r] * inv[r]);

    __syncthreads();  // Cs visible to all waves

    // ---- phase C: out-proj rank-128 update ----
    // A = Cs[32][128] (this t's two heads), B = wo rows wid*128.., cols t*128..
#pragma unroll
    for (int kc = 0; kc < 4; ++kc) {
      bf16x8 af[2];
#pragma unroll
      for (int mi = 0; mi < 2; ++mi)
        af[mi] = *reinterpret_cast<const bf16x8*>(
            &Cs[mi * 16 + row16][kc * 32 + kgrp * 8]);
      bf16x8 bfr[8];
#pragma unroll
      for (int ni = 0; ni < 8; ++ni)
        bfr[ni] = *reinterpret_cast<const bf16x8*>(
            &wo[(size_t)(wid * 128 + ni * 16 + row16) * 512 + t * 128 +
                kc * 32 + kgrp * 8]);
#pragma unroll
      for (int mi = 0; mi < 2; ++mi)
#pragma unroll
        for (int ni = 0; ni < 8; ++ni)
          oacc[mi][ni] = __builtin_amdgcn_mfma_f32_16x16x32_bf16(
              af[mi], bfr[ni], oacc[mi][ni], 0, 0, 0);
    }
    __syncthreads();  // protect Vt/Ps/Cs rewrite next t
  }

  // ---- epilogue: bias + fp32 store ----
#pragma unroll
  for (int ni = 0; ni < 8; ++ni) {
    const int col = wid * 128 + ni * 16 + row16;
    const float bv = b_out[col];
#pragma unroll
    for (int mi = 0; mi < 2; ++mi)
#pragma unroll
      for (int r2 = 0; r2 < 4; ++r2)
        out[(bS + q0 + mi * 16 + crow4 + r2) * 512 + col] =
            oacc[mi][ni][r2] + bv;
  }
}

extern "C" void kernel_launch(void* const* d_in, const int* in_sizes, int n_in,
                              void* d_out, int out_size, void* d_ws, size_t ws_size,
                              hipStream_t stream) {
  const float* x = (const float*)d_in[0];
  const float* w_in = (const float*)d_in[1];
  const float* b_in = (const float*)d_in[2];
  const float* w_out = (const float*)d_in[3];
  const float* b_out = (const float*)d_in[4];
  float* out = (float*)d_out;

  const int B = 2, S = 4096, D = 512;
  const int BS = B * S;  // 8192

  char* ws = (char*)d_ws;
  unsigned short* xb = (unsigned short*)(ws + 0);          //  8,388,608
  unsigned short* wbin = (unsigned short*)(ws + 8388608);  //  1,572,864
  unsigned short* wbo = (unsigned short*)(ws + 9961472);   //    524,288
  unsigned short* qkvb = (unsigned short*)(ws + 10485760); // 25,165,824

  // all fp32->bf16 converts in one launch
  cvt_all<<<2048, 256, 0, stream>>>(x, w_in, w_out, xb, wbin, wbo);

  // QKV projection: [8192,512] x [1536,512]^T -> bf16 [8192,1536]
  gemm_bt<<<dim3(12, 64), 256, 0, stream>>>(xb, wbin, b_in, qkvb, BS, 3 * D, D);

  // fused local attention + out projection -> fp32 d_out
  attn_oproj<<<dim3(S / 32, 2), 256, 0, stream>>>(qkvb, wbo, b_out, out, S);
}

// Round 20
// 53.427 us; speedup vs baseline: 1.2176x; 1.2176x over previous
//
#include <hip/hip_runtime.h>

typedef __attribute__((ext_vector_type(8))) short bf16x8;
typedef __attribute__((ext_vector_type(8))) unsigned short ushort8;
typedef __attribute__((ext_vector_type(4))) float f32x4;

static __device__ __forceinline__ unsigned short f2bf(float f) {
  union { float f; unsigned u; } v; v.f = f;
  unsigned r = v.u + 0x7FFFu + ((v.u >> 16) & 1u);
  return (unsigned short)(r >> 16);
}
static __device__ __forceinline__ int iclamp(int x, int lo, int hi) {
  return x < lo ? lo : (x > hi ? hi : x);
}
// async global->LDS, 16B per lane; LDS dest = wave-uniform base + lane*16
static __device__ __forceinline__ void gl_lds16(const unsigned short* g,
                                                unsigned short* l) {
  __builtin_amdgcn_global_load_lds(
      (const __attribute__((address_space(1))) void*)g,
      (__attribute__((address_space(3))) void*)l, 16, 0, 0);
}

// ---------------- fused fp32 -> bf16 converts (one launch) ----------------
__global__ void cvt_all(const float* __restrict__ x,
                        const float* __restrict__ w_in,
                        const float* __restrict__ w_out,
                        unsigned short* __restrict__ xb,
                        unsigned short* __restrict__ wbin,
                        unsigned short* __restrict__ wbo) {
  const int NX4 = 1048576, NWI4 = 196608, NWO4 = 65536;  // float4 counts
  const int total = NX4 + NWI4 + NWO4;
  for (int i = blockIdx.x * blockDim.x + threadIdx.x; i < total;
       i += gridDim.x * blockDim.x) {
    const float* src;
    unsigned short* dst;
    int o;
    if (i < NX4) {
      src = x; dst = xb; o = i;
    } else if (i < NX4 + NWI4) {
      src = w_in; dst = wbin; o = i - NX4;
    } else {
      src = w_out; dst = wbo; o = i - NX4 - NWI4;
    }
    float4 v = reinterpret_cast<const float4*>(src)[o];
    ushort4 u;
    u.x = f2bf(v.x); u.y = f2bf(v.y); u.z = f2bf(v.z); u.w = f2bf(v.w);
    reinterpret_cast<ushort4*>(dst)[o] = u;
  }
}

// ------- GEMM: C[M][N] = A[M][K](bf16) * B[N][K](bf16)^T + bias -------
// 2-phase double-buffer, gl_lds w16 pre-swizzled source, post-MFMA drain,
// one barrier per K-step. BK template param:
//   BK=64: one gl_lds = 8 rows x 64B, swizzle chunk ^= row&7
//   BK=32: one gl_lds = 16 rows x 64B, swizzle chunk ^= row&3
// OUT_BF16==1 (requires BM==128,BN==128): vectorized epilogue via C-restage.
template <int BM, int BN, int WM, int WN, int BK, int OUT_BF16>
__global__ __launch_bounds__(256) void gemm_bt(
    const unsigned short* __restrict__ A, const unsigned short* __restrict__ B,
    const float* __restrict__ bias, void* __restrict__ Cv,
    int M, int N, int K) {
  __shared__ unsigned short As[2][BM][BK];
  __shared__ unsigned short Bs[2][BN][BK];
  const int tid = threadIdx.x;
  const int lane = tid & 63;
  const int wid = tid >> 6;

  // XCD-aware bijective swizzle (grids here are multiples of 8)
  const int nwg = gridDim.x * gridDim.y;
  const int orig = blockIdx.y * gridDim.x + blockIdx.x;
  const int q = nwg >> 3, r = nwg & 7;
  const int xcd = orig & 7, lid = orig >> 3;
  const int swz = (xcd < r ? xcd * (q + 1) : r * (q + 1) + (xcd - r) * q) + lid;
  const int bm = (swz / gridDim.x) * BM;
  const int bn = (swz % gridDim.x) * BN;

  const int NWC = BN / WN;
  const int wr = (wid / NWC) * WM;
  const int wc = (wid % NWC) * WN;
  const int row16 = lane & 15;
  const int kgrp = lane >> 4;
  const int rsw = (BK == 64) ? (row16 & 7) : (row16 & 3);

  const int RPI = 1024 / (BK * 2);  // rows per gl_lds instr: 8 or 16
  const int lrow = (BK == 64) ? (lane >> 3) : (lane >> 2);
  const int lch = (BK == 64) ? ((lane & 7) ^ (lane >> 3))
                             : ((lane & 3) ^ ((lane >> 2) & 3));
  const int srA = wid * (BM / 4) + lrow;
  const int srB = wid * (BN / 4) + lrow;
  const unsigned short* gA = A + (size_t)(bm + srA) * K + lch * 8;
  const unsigned short* gB = B + (size_t)(bn + srB) * K + lch * 8;
  const size_t KR = (size_t)RPI * K;

#define STAGE(buf, k0)                                                     \
  {                                                                        \
    _Pragma("unroll") for (int j = 0; j < BM / (4 * RPI); ++j)             \
        gl_lds16(gA + j * KR + (k0),                                       \
                 &As[buf][wid * (BM / 4) + j * RPI][0]);                   \
    _Pragma("unroll") for (int j = 0; j < BN / (4 * RPI); ++j)             \
        gl_lds16(gB + j * KR + (k0),                                       \
                 &Bs[buf][wid * (BN / 4) + j * RPI][0]);                   \
  }

  f32x4 acc[WM / 16][WN / 16] = {};

  STAGE(0, 0);
  asm volatile("s_waitcnt vmcnt(0)" ::: "memory");
  __builtin_amdgcn_s_barrier();

  const int NT = K / BK;
  for (int t = 0; t < NT; ++t) {
    const int cur = t & 1;
    if (t + 1 < NT) STAGE(cur ^ 1, (t + 1) * BK);
    bf16x8 af[WM / 16][BK / 32], bfr[WN / 16][BK / 32];
#pragma unroll
    for (int mi = 0; mi < WM / 16; ++mi)
#pragma unroll
      for (int kh = 0; kh < BK / 32; ++kh)
        af[mi][kh] = *reinterpret_cast<const bf16x8*>(
            &As[cur][wr + mi * 16 + row16][((kh * 4 + kgrp) ^ rsw) * 8]);
#pragma unroll
    for (int ni = 0; ni < WN / 16; ++ni)
#pragma unroll
      for (int kh = 0; kh < BK / 32; ++kh)
        bfr[ni][kh] = *reinterpret_cast<const bf16x8*>(
            &Bs[cur][wc + ni * 16 + row16][((kh * 4 + kgrp) ^ rsw) * 8]);
#pragma unroll
    for (int kh = 0; kh < BK / 32; ++kh)
#pragma unroll
      for (int mi = 0; mi < WM / 16; ++mi)
#pragma unroll
        for (int ni = 0; ni < WN / 16; ++ni)
          acc[mi][ni] = __builtin_amdgcn_mfma_f32_16x16x32_bf16(
              af[mi][kh], bfr[ni][kh], acc[mi][ni], 0, 0, 0);
    // drain next-tile loads AFTER compute (latency covered), then barrier
    asm volatile("s_waitcnt vmcnt(0)" ::: "memory");
    __builtin_amdgcn_s_barrier();
  }
#undef STAGE

  if constexpr (OUT_BF16 == 1) {
    // vectorized epilogue: restage C tile (bias applied) in As (now free)
    unsigned short* Cs = &As[0][0][0];  // >= 128*128 ushorts
#pragma unroll
    for (int ni = 0; ni < WN / 16; ++ni) {
      const float bv = bias[bn + wc + ni * 16 + row16];
#pragma unroll
      for (int mi = 0; mi < WM / 16; ++mi)
#pragma unroll
        for (int r2 = 0; r2 < 4; ++r2)
          Cs[(wr + mi * 16 + kgrp * 4 + r2) * 128 + wc + ni * 16 + row16] =
              f2bf(acc[mi][ni][r2] + bv);
    }
    __syncthreads();
    unsigned short* Cq = reinterpret_cast<unsigned short*>(Cv);
#pragma unroll
    for (int j = 0; j < 8; ++j) {
      const int row = j * 16 + (tid >> 4);
      const int col = (tid & 15) * 8;
      ushort8 v = *reinterpret_cast<const ushort8*>(&Cs[row * 128 + col]);
      *reinterpret_cast<ushort8*>(&Cq[(size_t)(bm + row) * N + bn + col]) = v;
    }
  } else {
#pragma unroll
    for (int ni = 0; ni < WN / 16; ++ni) {
      const int gcol = bn + wc + ni * 16 + row16;
      const float bv = bias[gcol];
#pragma unroll
      for (int mi = 0; mi < WM / 16; ++mi) {
#pragma unroll
        for (int r2 = 0; r2 < 4; ++r2) {
          const int grow = bm + wr + mi * 16 + kgrp * 4 + r2;
          reinterpret_cast<float*>(Cv)[(size_t)grow * N + gcol] =
              acc[mi][ni][r2] + bv;
        }
      }
    }
  }
}

// ---------------- local (banded) attention, v3 + XCD-chunked grid ----------------
// (r13/r14 best version: 64 q/block, 4 waves, coalesced ctx store, no setprio)
__global__ __launch_bounds__(256) void attn_local(
    const unsigned short* __restrict__ qkv, unsigned short* __restrict__ ctx,
    int S) {
  __shared__ unsigned Vt[64][76];            // 19456 B
  __shared__ unsigned short Ps[4][16][104];  // 13312 B

  const int tid = threadIdx.x;
  const int lane = tid & 63;
  const int wid = tid >> 6;

  // bijective XCD-chunked swizzle: nwg = (S/64)*16, multiple of 8
  const int nqb = S >> 6;
  const int nwg = nqb * 16;
  const int orig = blockIdx.y * gridDim.x + blockIdx.x;
  const int cpx = nwg >> 3;
  const int swzb = (orig & 7) * cpx + (orig >> 3);
  const int q0 = (swzb % nqb) * 64;
  const int bh = swzb / nqb;
  const int b = bh >> 3;
  const int h = bh & 7;

  const int row16 = lane & 15;
  const int kgrp = lane >> 4;
  const size_t bS = (size_t)b * S;

  // ---- stage V transposed (packed key pairs) ----
  {
    const int k2 = tid >> 2;
    const int dq = (tid & 3) * 16;
    const int ra = iclamp(q0 - 32 + 2 * k2, 0, S - 1);
    const int rb = iclamp(q0 - 32 + 2 * k2 + 1, 0, S - 1);
    const unsigned short* pa = qkv + (bS + ra) * 1536 + 1024 + h * 64 + dq;
    const unsigned short* pb = qkv + (bS + rb) * 1536 + 1024 + h * 64 + dq;
    ushort8 a0 = reinterpret_cast<const ushort8*>(pa)[0];
    ushort8 a1 = reinterpret_cast<const ushort8*>(pa)[1];
    ushort8 b0 = reinterpret_cast<const ushort8*>(pb)[0];
    ushort8 b1 = reinterpret_cast<const ushort8*>(pb)[1];
#pragma unroll
    for (int d = 0; d < 8; ++d) {
      Vt[dq + d][k2] = (unsigned)a0[d] | ((unsigned)b0[d] << 16);
      Vt[dq + 8 + d][k2] = (unsigned)a1[d] | ((unsigned)b1[d] << 16);
    }
    const int zr = tid >> 2;
    const int zc = 64 + (tid & 3) * 2;
    Vt[zr][zc] = 0u;
    Vt[zr][zc + 1] = 0u;
  }

  // ---- Q fragments (direct from global) ----
  bf16x8 qf0, qf1;
  {
    const unsigned short* qp =
        qkv + (bS + q0 + wid * 16 + row16) * 1536 + h * 64;
    qf0 = *reinterpret_cast<const bf16x8*>(qp + kgrp * 8);
    qf1 = *reinterpret_cast<const bf16x8*>(qp + 32 + kgrp * 8);
  }

  // ---- QK^T: 5 key tiles, K direct from global (clamped rows) ----
  f32x4 sc[5];
#pragma unroll
  for (int t = 0; t < 5; ++t) {
    const int key = iclamp(q0 - 32 + (wid + t) * 16 + row16, 0, S - 1);
    const unsigned short* kp = qkv + (bS + key) * 1536 + 512 + h * 64;
    bf16x8 kf0 = *reinterpret_cast<const bf16x8*>(kp + kgrp * 8);
    bf16x8 kf1 = *reinterpret_cast<const bf16x8*>(kp + 32 + kgrp * 8);
    f32x4 s = {0.f, 0.f, 0.f, 0.f};
    s = __builtin_amdgcn_mfma_f32_16x16x32_bf16(qf0, kf0, s, 0, 0, 0);
    s = __builtin_amdgcn_mfma_f32_16x16x32_bf16(qf1, kf1, s, 0, 0, 0);
    sc[t] = s;
  }

  // ---- mask + softmax ----
  const int ccol = row16;
  const int crow4 = kgrp * 4;
  float rm[4] = {-INFINITY, -INFINITY, -INFINITY, -INFINITY};
#pragma unroll
  for (int t = 0; t < 5; ++t)
#pragma unroll
    for (int r = 0; r < 4; ++r) {
      const int key_abs = q0 - 32 + (wid + t) * 16 + ccol;
      const int diff = -32 + t * 16 + ccol - crow4 - r;
      float s = sc[t][r] * 0.125f;
      const bool valid =
          (diff >= -32) && (diff <= 32) && (key_abs >= 0) && (key_abs < S);
      s = valid ? s : -INFINITY;
      sc[t][r] = s;
      rm[r] = fmaxf(rm[r], s);
    }
#pragma unroll
  for (int off = 1; off < 16; off <<= 1)
#pragma unroll
    for (int r = 0; r < 4; ++r) rm[r] = fmaxf(rm[r], __shfl_xor(rm[r], off, 64));
  float rs[4] = {0.f, 0.f, 0.f, 0.f};
#pragma unroll
  for (int t = 0; t < 5; ++t)
#pragma unroll
    for (int r = 0; r < 4; ++r) {
      const float p = __expf(sc[t][r] - rm[r]);
      sc[t][r] = p;
      rs[r] += p;
    }
#pragma unroll
  for (int off = 1; off < 16; off <<= 1)
#pragma unroll
    for (int r = 0; r < 4; ++r) rs[r] += __shfl_xor(rs[r], off, 64);

  // ---- P -> LDS (bf16), zero-pad keys 80..95 ----
#pragma unroll
  for (int t = 0; t < 5; ++t)
#pragma unroll
    for (int r = 0; r < 4; ++r)
      Ps[wid][crow4 + r][t * 16 + ccol] = f2bf(sc[t][r]);
#pragma unroll
  for (int j = 0; j < 4; ++j) Ps[wid][row16][80 + kgrp * 4 + j] = 0;

  __syncthreads();

  // ---- PV: ctx[16x64] = P[16x96] * V[96x64] ----
  f32x4 cacc[4] = {};
#pragma unroll
  for (int kc = 0; kc < 3; ++kc) {
    bf16x8 pf = *reinterpret_cast<const bf16x8*>(&Ps[wid][row16][kc * 32 + kgrp * 8]);
#pragma unroll
    for (int ni = 0; ni < 4; ++ni) {
      bf16x8 vf = *reinterpret_cast<const bf16x8*>(
          &Vt[ni * 16 + row16][wid * 8 + kc * 16 + kgrp * 4]);
      cacc[ni] = __builtin_amdgcn_mfma_f32_16x16x32_bf16(pf, vf, cacc[ni], 0, 0, 0);
    }
  }

  // ---- normalize; restage tile in wave-private Ps; coalesced store ----
  float inv[4];
#pragma unroll
  for (int r = 0; r < 4; ++r) inv[r] = 1.0f / rs[r];
#pragma unroll
  for (int ni = 0; ni < 4; ++ni)
#pragma unroll
    for (int r = 0; r < 4; ++r)
      Ps[wid][crow4 + r][ni * 16 + ccol] = f2bf(cacc[ni][r] * inv[r]);
  // wave-private buffer: write->read ordered by lgkmcnt (no barrier needed)
#pragma unroll
  for (int j = 0; j < 2; ++j) {
    ushort8 vv = *reinterpret_cast<const ushort8*>(
        &Ps[wid][j * 8 + (lane >> 3)][(lane & 7) * 8]);
    *reinterpret_cast<ushort8*>(
        &ctx[(bS + q0 + wid * 16 + j * 8 + (lane >> 3)) * 512 + h * 64 +
             (lane & 7) * 8]) = vv;
  }
}

extern "C" void kernel_launch(void* const* d_in, const int* in_sizes, int n_in,
                              void* d_out, int out_size, void* d_ws, size_t ws_size,
                              hipStream_t stream) {
  const float* x = (const float*)d_in[0];
  const float* w_in = (const float*)d_in[1];
  const float* b_in = (const float*)d_in[2];
  const float* w_out = (const float*)d_in[3];
  const float* b_out = (const float*)d_in[4];
  float* out = (float*)d_out;

  const int B = 2, S = 4096, D = 512;
  const int BS = B * S;  // 8192

  char* ws = (char*)d_ws;
  unsigned short* xb = (unsigned short*)(ws + 0);          //  8,388,608
  unsigned short* wbin = (unsigned short*)(ws + 8388608);  //  1,572,864
  unsigned short* wbo = (unsigned short*)(ws + 9961472);   //    524,288
  unsigned short* qkvb = (unsigned short*)(ws + 10485760); // 25,165,824
  unsigned short* ctxb = (unsigned short*)(ws + 35651584); //  8,388,608

  // all fp32->bf16 converts in one launch
  cvt_all<<<2048, 256, 0, stream>>>(x, w_in, w_out, xb, wbin, wbo);

  // QKV projection: [8192,512] x [1536,512]^T -> bf16 [8192,1536]
  // BK=32 dbuf: LDS 32 KB -> ~4 blocks/CU (r14-proven best)
  gemm_bt<128, 128, 64, 64, 32, 1>
      <<<dim3(12, 64), 256, 0, stream>>>(xb, wbin, b_in, qkvb, BS, 3 * D, D);

  // local attention -> ctx bf16 [8192,512]; 64 q/block (r13 best config)
  attn_local<<<dim3(S / 64, 16), 256, 0, stream>>>(qkvb, ctxb, S);

  // out projection: [8192,512] x [512,512]^T -> fp32 d_out (r14 config)
  gemm_bt<64, 128, 32, 64, 64, 0>
      <<<dim3(4, 128), 256, 0, stream>>>(ctxb, wbo, b_out, out, BS, D, D);
}